// Round 7
// baseline (104.368 us; speedup 1.0000x reference)
//
#include <hip/hip_runtime.h>

constexpr int SLN = 512, BSZ = 128, TAG = 32;
constexpr float INVLN2 = 1.4426950408889634f;
constexpr float LN2f = 0.6931471805599453f;

__device__ __forceinline__ float exp2_fast(float x) { return __builtin_amdgcn_exp2f(x); }
__device__ __forceinline__ float log2_fast(float x) { return __builtin_amdgcn_logf(x); }

__device__ __forceinline__ void pl16_swap(float& x, float& y) {
  asm("v_permlane16_swap_b32 %0, %1" : "+v"(x), "+v"(y));
}
__device__ __forceinline__ void pl32_swap(float& x, float& y) {
  asm("v_permlane32_swap_b32 %0, %1" : "+v"(x), "+v"(y));
}
// async global->LDS, 16B per lane
__device__ __forceinline__ void gload_lds16(const float* g, float* lds_uniform) {
  __builtin_amdgcn_global_load_lds(
      (const __attribute__((address_space(1))) unsigned int*)g,
      (__attribute__((address_space(3))) unsigned int*)lds_uniform, 16, 0, 0);
}

// Fused broadcast-FMA matvec, 4 accumulators (dep distance 4 insts covers DPP
// result latency; tree-combined by the caller). s_nop 1 covers the VALU-write ->
// DPP-source-read hazard on ucur.
__device__ __forceinline__ void matvec16x4(float& p0, float& p1, float& p2, float& p3,
                                           float ucur, const float (&E)[16]) {
  asm("s_nop 1\n\t"
      "v_mul_f32_dpp  %0, %4, %5  row_newbcast:0  row_mask:0xf bank_mask:0xf\n\t"
      "v_mul_f32_dpp  %1, %4, %6  row_newbcast:1  row_mask:0xf bank_mask:0xf\n\t"
      "v_mul_f32_dpp  %2, %4, %7  row_newbcast:2  row_mask:0xf bank_mask:0xf\n\t"
      "v_mul_f32_dpp  %3, %4, %8  row_newbcast:3  row_mask:0xf bank_mask:0xf\n\t"
      "v_fmac_f32_dpp %0, %4, %9  row_newbcast:4  row_mask:0xf bank_mask:0xf\n\t"
      "v_fmac_f32_dpp %1, %4, %10 row_newbcast:5  row_mask:0xf bank_mask:0xf\n\t"
      "v_fmac_f32_dpp %2, %4, %11 row_newbcast:6  row_mask:0xf bank_mask:0xf\n\t"
      "v_fmac_f32_dpp %3, %4, %12 row_newbcast:7  row_mask:0xf bank_mask:0xf\n\t"
      "v_fmac_f32_dpp %0, %4, %13 row_newbcast:8  row_mask:0xf bank_mask:0xf\n\t"
      "v_fmac_f32_dpp %1, %4, %14 row_newbcast:9  row_mask:0xf bank_mask:0xf\n\t"
      "v_fmac_f32_dpp %2, %4, %15 row_newbcast:10 row_mask:0xf bank_mask:0xf\n\t"
      "v_fmac_f32_dpp %3, %4, %16 row_newbcast:11 row_mask:0xf bank_mask:0xf\n\t"
      "v_fmac_f32_dpp %0, %4, %17 row_newbcast:12 row_mask:0xf bank_mask:0xf\n\t"
      "v_fmac_f32_dpp %1, %4, %18 row_newbcast:13 row_mask:0xf bank_mask:0xf\n\t"
      "v_fmac_f32_dpp %2, %4, %19 row_newbcast:14 row_mask:0xf bank_mask:0xf\n\t"
      "v_fmac_f32_dpp %3, %4, %20 row_newbcast:15 row_mask:0xf bank_mask:0xf"
      : "=&v"(p0), "=&v"(p1), "=&v"(p2), "=&v"(p3)
      : "v"(ucur), "v"(E[0]), "v"(E[1]), "v"(E[2]), "v"(E[3]), "v"(E[4]),
        "v"(E[5]), "v"(E[6]), "v"(E[7]), "v"(E[8]), "v"(E[9]), "v"(E[10]),
        "v"(E[11]), "v"(E[12]), "v"(E[13]), "v"(E[14]), "v"(E[15]));
}

// Lane mapping: row r = lane>>4, i = lane&15; kh = r>>1; j = i + 16*(r&1).
// ucur row r holds a[16*kh + i] (rows [A,A,B,B]); one step:
// matvec (per-kh partial) -> pl32_swap+add (combine k-halves; direction-proof)
// -> *emf -> pl16_swap+cndmask rebuild of [A,A,B,B].
__device__ __forceinline__ float crf_step3(float ucur, const float (&E)[16],
                                           float emf, bool selx) {
  float p0, p1, p2, p3;
  matvec16x4(p0, p1, p2, p3, ucur, E);
  float x = (p0 + p1) + (p2 + p3), y = x;
  pl32_swap(x, y);
  const float a = (x + y) * emf;   // j-layout [J0,J1,J0,J1]
  float xx = a, yy = a;
  pl16_swap(xx, yy);               // one reg = all-J0 rows, other = all-J1 (probed)
  return selx ? xx : yy;
}

// Block b < BSZ: forward scan (log-partition) for batch b -> ws[b]
// Block b >= BSZ: gold-path score for batch b-BSZ        -> ws[BSZ + b]
__global__ __launch_bounds__(64, 1) void crf_fwd_kernel(
    const float* __restrict__ emission, const int* __restrict__ length,
    const int* __restrict__ target, const float* __restrict__ transition,
    const float* __restrict__ start_tr, const float* __restrict__ end_tr,
    float* __restrict__ ws) {
  const int blk = blockIdx.x;
  const int lane = threadIdx.x;
  __shared__ float smem[SLN * TAG];   // 64 KB: this batch's emission slice [t][j]

  if (blk < BSZ) {
    const int b = blk;

    // stage emission[b] into LDS: 64 x (64 lanes x 16B) = 64 KB, fire-and-forget
    const float* gembase = emission + (size_t)b * SLN * TAG;
    {
      const float* gl = gembase + lane * 4;
#pragma unroll
      for (int i = 0; i < 64; ++i)
        gload_lds16(gl + i * 256, &smem[i * 256]);
    }

    const int len = length[b];                       // in [2, 512]
    const int r = lane >> 4;
    const int j = (lane & 15) + 16 * (r & 1);        // rows [J0,J1,J0,J1]
    const int kh = lane >> 5;                        // k-half = r>>1

    // one-time probe of permlane16_swap output ordering
    int pv = lane, qv = lane;
    asm("v_permlane16_swap_b32 %0, %1" : "+v"(pv), "+v"(qv));
    const bool s1 = (__builtin_amdgcn_readfirstlane(pv) == 0);
    const bool selx = (lane < 32) == s1;             // lanes<32 take the all-J0 register

    // E[n] = exp(transition[16*kh + n][j]), VGPR-resident (overlaps staging)
    float E[16];
#pragma unroll
    for (int n = 0; n < 16; ++n)
      E[n] = exp2_fast(transition[(16 * kh + n) * TAG + j] * INVLN2);
    const float st = start_tr[j];

    asm volatile("s_waitcnt vmcnt(0)" ::: "memory"); // staging done (single wave)

    // alpha in linear base-2 domain; carry only ucur ([A,A,B,B] layout)
    float base = 0.f;
    float ucur;
    {
      const float a0 = exp2_fast((st + smem[j]) * INVLN2);   // j-layout
      float xx = a0, yy = a0;
      pl16_swap(xx, yy);
      ucur = selx ? xx : yy;
    }

    // ping-pong emission buffers + emf precomputed one full block ahead
    float bufP[8], bufQ[8], emfP[8], emfQ[8];
#pragma unroll
    for (int u = 0; u < 8; ++u) {
      bufP[u] = smem[(1 + u) * TAG + j];
      emfP[u] = exp2_fast(bufP[u] * INVLN2);
    }

    const int steps = len - 1;                       // >= 1
    const int nfull = steps >> 3;
    const int tail = steps & 7;
    const int npair = nfull >> 1;

    // exact power-of-two renorm (lane0 of ucur = a[0]); base += e, exact
    auto renorm = [&]() {
      const unsigned ab = (unsigned)__builtin_amdgcn_readfirstlane(__float_as_int(ucur));
      const int e = (int)((ab >> 23) & 255u) - 127;
      ucur *= __int_as_float((127 - e) << 23);
      base += (float)e;
    };

    // one 8-step block: prefetch next block into bufN (pinned early by
    // sched_barrier so the scheduler cannot sink the ds_reads), run 8 steps
    // from ready emfC, fill emfN off-chain as the prefetch lands.
    auto do_block = [&](const float (&emfC)[8], float (&bufN)[8], float (&emfN)[8],
                        int t0) {
#pragma unroll
      for (int u = 0; u < 8; ++u) {
        int tp = t0 + 8 + u; tp = tp < SLN ? tp : SLN - 1;
        bufN[u] = smem[tp * TAG + j];
      }
      __builtin_amdgcn_sched_barrier(0);   // ds_reads issue before the steps
#pragma unroll
      for (int u = 0; u < 8; ++u) {
        ucur = crf_step3(ucur, E, emfC[u], selx);
        emfN[u] = exp2_fast(bufN[u] * INVLN2);   // off-chain, data arrived by now
      }
      renorm();
    };

    int t0 = 1;
    for (int p = 0; p < npair; ++p) {
      do_block(emfP, bufQ, emfQ, t0); t0 += 8;
      do_block(emfQ, bufP, emfP, t0); t0 += 8;
    }
    const bool odd = (nfull & 1) != 0;
    if (odd) { do_block(emfP, bufQ, emfQ, t0); t0 += 8; }

    if (tail) {
      // current emf array depends on parity; duplicate code, no runtime indexing
      if (odd) {
#pragma unroll
        for (int u = 0; u < 7; ++u) {
          const float nu = crf_step3(ucur, E, emfQ[u], selx);
          ucur = (u < tail) ? nu : ucur;           // wave-uniform mask
        }
      } else {
#pragma unroll
        for (int u = 0; u < 7; ++u) {
          const float nu = crf_step3(ucur, E, emfP[u], selx);
          ucur = (u < tail) ? nu : ucur;
        }
      }
    }

    // lane holds a[16*(lane>>5) + (lane&15)], each j appearing twice:
    // logZ = ln2 * (base + log2(sum_lanes a*exp(end)) - 1)
    const int jj = (lane & 15) + 16 * (lane >> 5);
    float v = ucur * exp2_fast(end_tr[jj] * INVLN2);
#pragma unroll
    for (int m = 32; m >= 1; m >>= 1) v += __shfl_xor(v, m, 64);
    if (lane == 0) ws[b] = LN2f * (base + log2_fast(v) - 1.0f);

  } else {
    const int b = blk - BSZ;
    const int len = length[b];
    const int* tg = target + b * SLN;
    float s = 0.f;
#pragma unroll
    for (int k0 = 0; k0 < SLN; k0 += 64) {
      const int k = k0 + lane;
      if (k < len) {
        const int tk = tg[k];
        s += emission[((size_t)b * SLN + k) * TAG + tk];
        if (k >= 1) s += transition[tg[k - 1] * TAG + tk];
      }
    }
#pragma unroll
    for (int m = 32; m >= 1; m >>= 1) s += __shfl_xor(s, m, 64);
    if (lane == 0) {
      s += start_tr[tg[0]] + end_tr[tg[len - 1]];
      ws[BSZ + b] = s;
    }
  }
}

__global__ __launch_bounds__(64) void crf_reduce_kernel(const float* __restrict__ ws,
                                                        float* __restrict__ out) {
  const int lane = threadIdx.x;
  float v = (ws[lane] - ws[BSZ + lane]) + (ws[lane + 64] - ws[BSZ + lane + 64]);
#pragma unroll
  for (int m = 32; m >= 1; m >>= 1) v += __shfl_xor(v, m, 64);
  if (lane == 0) out[0] = v;
}

extern "C" void kernel_launch(void* const* d_in, const int* in_sizes, int n_in,
                              void* d_out, int out_size, void* d_ws, size_t ws_size,
                              hipStream_t stream) {
  const float* emission   = (const float*)d_in[0];
  const int*   length     = (const int*)d_in[1];
  const int*   target     = (const int*)d_in[2];
  const float* transition = (const float*)d_in[3];
  const float* start_tr   = (const float*)d_in[4];
  const float* end_tr     = (const float*)d_in[5];
  float* ws = (float*)d_ws;   // 256 floats: [0,128) logZ, [128,256) score

  crf_fwd_kernel<<<2 * BSZ, 64, 0, stream>>>(emission, length, target, transition,
                                             start_tr, end_tr, ws);
  crf_reduce_kernel<<<1, 64, 0, stream>>>(ws, (float*)d_out);
}